// Round 2
// baseline (474.364 us; speedup 1.0000x reference)
//
#include <hip/hip_runtime.h>

// SpikeLayer: V_t = reset(V_{t-1} + I_t), reset(x) = (|x|>1 ? 0 : x)
// inputs: [T*B, D] fp32, T=16, B=512, D=8192. out_t = V_t. Memory-bound stream:
// 256 MB in + 256 MB out. Floor ~81 us at 6.3 TB/s; less if input stays L3-resident.
//
// This version:
//  - 2 independent float4 chains per thread (slice halves) -> ~4 VMEM in flight
//  - explicit next-t register prefetch (breaks the load->wait->store serial chain)
//  - non-temporal stores (clang ext_vector_type, NOT HIP float4 — builtin rejects
//    class types): output is write-once/never-read, keep it OUT of L2/L3 so the
//    256 MB input can stay L3-resident across iterations.

typedef float f32x4 __attribute__((ext_vector_type(4)));

constexpr int TIMES = 16;
constexpr long long STEP_F4 = (512LL * 8192LL) / 4;  // f32x4 per t-slice = 1048576
constexpr long long HALF_F4 = STEP_F4 / 2;           // 524288

__device__ __forceinline__ f32x4 step_reset(f32x4 V, f32x4 I) {
    V += I;
    V.x = (fabsf(V.x) > 1.0f) ? 0.0f : V.x;
    V.y = (fabsf(V.y) > 1.0f) ? 0.0f : V.y;
    V.z = (fabsf(V.z) > 1.0f) ? 0.0f : V.z;
    V.w = (fabsf(V.w) > 1.0f) ? 0.0f : V.w;
    return V;
}

__global__ __launch_bounds__(256) void SpikeLayer_88553635709313_kernel(
    const f32x4* __restrict__ in, f32x4* __restrict__ out) {
    long long idx = (long long)blockIdx.x * blockDim.x + threadIdx.x;  // [0, HALF_F4)
    long long pa = idx;            // chain A: first half of each t-slice
    long long pb = idx + HALF_F4;  // chain B: second half of each t-slice

    f32x4 Va = (f32x4)0.0f;
    f32x4 Vb = (f32x4)0.0f;

    // Prime the pipeline: loads for t=0 in flight.
    f32x4 Ia = in[pa];
    f32x4 Ib = in[pb];

#pragma unroll
    for (int t = 0; t < TIMES; ++t) {
        // Issue next-slice loads BEFORE consuming current ones: keeps 2 loads
        // + 2 stores in flight per thread instead of serializing on latency.
        f32x4 Na = Ia, Nb = Ib;
        if (t < TIMES - 1) {
            Na = in[pa + STEP_F4];
            Nb = in[pb + STEP_F4];
        }
        Va = step_reset(Va, Ia);
        Vb = step_reset(Vb, Ib);
        __builtin_nontemporal_store(Va, &out[pa]);
        __builtin_nontemporal_store(Vb, &out[pb]);
        pa += STEP_F4;
        pb += STEP_F4;
        Ia = Na;
        Ib = Nb;
    }
}

extern "C" void kernel_launch(void* const* d_in, const int* in_sizes, int n_in,
                              void* d_out, int out_size, void* d_ws, size_t ws_size,
                              hipStream_t stream) {
    const f32x4* in = (const f32x4*)d_in[0];
    f32x4* out = (f32x4*)d_out;
    const int threads = 256;
    const int blocks = (int)(HALF_F4 / threads);  // 2048
    SpikeLayer_88553635709313_kernel<<<blocks, threads, 0, stream>>>(in, out);
}

// Round 3
// 451.148 us; speedup vs baseline: 1.0515x; 1.0515x over previous
//
#include <hip/hip_runtime.h>

// SpikeLayer: V_t = reset(V_{t-1} + I_t), reset(x) = (|x|>1 ? 0 : x)
// inputs: [T*B, D] fp32, T=16, B=512, D=8192. out_t = V_t.
// Memory-bound stream: 256 MB in + 256 MB out; ~81 us floor at 6.3 TB/s.
//
// R3: max read MLP. The 16 per-thread loads are independent (only the V
// accumulation is serial), so issue ALL 16 up front into registers, then do
// the serial compute + stream the stores. This turns the per-iteration
// load->vmcnt(0)->store round-trip (R0: ~1 load in flight/wave, 2.4 TB/s)
// into a copy-like 16-deep read burst per wave. Plain stores (nt regressed
// in R2). Static-indexed I[] + full unroll -> stays in VGPRs (no scratch).

typedef float f32x4 __attribute__((ext_vector_type(4)));

constexpr int TIMES = 16;
constexpr long long STEP_F4 = (512LL * 8192LL) / 4;  // f32x4 per t-slice = 1048576

__global__ __launch_bounds__(256) void SpikeLayer_88553635709313_kernel(
    const f32x4* __restrict__ in, f32x4* __restrict__ out) {
    long long idx = (long long)blockIdx.x * blockDim.x + threadIdx.x;  // [0, STEP_F4)
    const f32x4* __restrict__ ip = in + idx;
    f32x4* __restrict__ op = out + idx;

    // Phase 1: issue all 16 slice loads back-to-back (16 KB in flight/wave).
    f32x4 I[TIMES];
#pragma unroll
    for (int t = 0; t < TIMES; ++t) {
        I[t] = ip[(long long)t * STEP_F4];
    }

    // Phase 2: serial accumulate + reset, stream stores out.
    f32x4 V = (f32x4)0.0f;
#pragma unroll
    for (int t = 0; t < TIMES; ++t) {
        V += I[t];
        V.x = (fabsf(V.x) > 1.0f) ? 0.0f : V.x;
        V.y = (fabsf(V.y) > 1.0f) ? 0.0f : V.y;
        V.z = (fabsf(V.z) > 1.0f) ? 0.0f : V.z;
        V.w = (fabsf(V.w) > 1.0f) ? 0.0f : V.w;
        op[(long long)t * STEP_F4] = V;
    }
}

extern "C" void kernel_launch(void* const* d_in, const int* in_sizes, int n_in,
                              void* d_out, int out_size, void* d_ws, size_t ws_size,
                              hipStream_t stream) {
    const f32x4* in = (const f32x4*)d_in[0];
    f32x4* out = (f32x4*)d_out;
    const int threads = 256;
    const int blocks = (int)(STEP_F4 / threads);  // 4096
    SpikeLayer_88553635709313_kernel<<<blocks, threads, 0, stream>>>(in, out);
}

// Round 4
// 425.618 us; speedup vs baseline: 1.1145x; 1.0600x over previous
//
#include <hip/hip_runtime.h>

// SpikeLayer: V_t = reset(V_{t-1} + I_t), reset(x) = (|x|>1 ? 0 : x)
// inputs: [T*B, D] fp32, T=16, B=512, D=8192. out_t = V_t.
// Logical traffic 512 MB; ~81 us floor at 6.3 TB/s.
//
// R4: DRAM stream-locality fix. R0/R3 ran ~2.4 TB/s HBM regardless of MLP depth:
// 16K waves each nibbling 1-KB chunks from 32 distinct 16-MB-apart regions =
// ~10K concurrent short streams -> row-buffer thrash. (Fill kernel: few long
// sequential streams -> 6.5 TB/s.) Fix: K=8 f32x4 columns per thread, V[8]
// carried in regs across t. Per t-slice a block touches one contiguous 32-KB
// run (8 back-to-back 4-KB wave-loads), grid drops 8x to 512 blocks ->
// ~2K long sequential streams instead of ~10K 1-KB ones. Same coalescing,
// all static indexing (regs, no scratch).

typedef float f32x4 __attribute__((ext_vector_type(4)));

constexpr int TIMES = 16;
constexpr int K = 8;  // f32x4 columns per thread
constexpr long long STEP_F4 = (512LL * 8192LL) / 4;  // f32x4 per t-slice = 1048576
constexpr int THREADS = 256;
// block covers THREADS*K = 2048 consecutive f32x4 (32 KB) per slice; grid = 512

__device__ __forceinline__ void step_reset(f32x4& V, f32x4 I) {
    V += I;
    V.x = (fabsf(V.x) > 1.0f) ? 0.0f : V.x;
    V.y = (fabsf(V.y) > 1.0f) ? 0.0f : V.y;
    V.z = (fabsf(V.z) > 1.0f) ? 0.0f : V.z;
    V.w = (fabsf(V.w) > 1.0f) ? 0.0f : V.w;
}

__global__ __launch_bounds__(THREADS) void SpikeLayer_88553635709313_kernel(
    const f32x4* __restrict__ in, f32x4* __restrict__ out) {
    const long long base =
        (long long)blockIdx.x * (THREADS * K) + threadIdx.x;  // k=0 column
    const f32x4* __restrict__ ip = in + base;
    f32x4* __restrict__ op = out + base;

    f32x4 V[K];
#pragma unroll
    for (int k = 0; k < K; ++k) V[k] = (f32x4)0.0f;

    for (int t = 0; t < TIMES; ++t) {
        const long long toff = (long long)t * STEP_F4;
        f32x4 I[K];
        // 8 back-to-back loads: one contiguous 32-KB block-run per slice.
#pragma unroll
        for (int k = 0; k < K; ++k) I[k] = ip[toff + k * THREADS];
#pragma unroll
        for (int k = 0; k < K; ++k) {
            step_reset(V[k], I[k]);
            op[toff + k * THREADS] = V[k];
        }
    }
}

extern "C" void kernel_launch(void* const* d_in, const int* in_sizes, int n_in,
                              void* d_out, int out_size, void* d_ws, size_t ws_size,
                              hipStream_t stream) {
    const f32x4* in = (const f32x4*)d_in[0];
    f32x4* out = (f32x4*)d_out;
    const int blocks = (int)(STEP_F4 / (THREADS * K));  // 512
    SpikeLayer_88553635709313_kernel<<<blocks, THREADS, 0, stream>>>(in, out);
}

// Round 5
// 425.075 us; speedup vs baseline: 1.1160x; 1.0013x over previous
//
#include <hip/hip_runtime.h>

// SpikeLayer: V_t = reset(V_{t-1} + I_t), reset(x) = (|x|>1 ? 0 : x)
// inputs: [T*B, D] fp32, T=16, B=512, D=8192. out_t = V_t.
// Logical traffic 512 MB; ~81 us floor at 6.3 TB/s.
//
// R5: extend the R4 stream-locality win (1KB->32KB runs: 164->~139us kernel).
// Per-slice contiguous run per block 32KB -> 64KB, concurrent streams halved:
// 512 threads/block, K=8 f32x4 per thread, grid=256 (1 block/CU, 8 waves).
// Same coalescing (lane i reads base+i), all static register indexing.
// __restrict__ lets the compiler hoist slice t+1 loads over slice t stores.

typedef float f32x4 __attribute__((ext_vector_type(4)));

constexpr int TIMES = 16;
constexpr int K = 8;          // f32x4 columns per thread
constexpr int THREADS = 512;  // block covers THREADS*K = 4096 f32x4 = 64 KB/slice
constexpr long long STEP_F4 = (512LL * 8192LL) / 4;  // f32x4 per t-slice = 1048576

__device__ __forceinline__ void step_reset(f32x4& V, f32x4 I) {
    V += I;
    V.x = (fabsf(V.x) > 1.0f) ? 0.0f : V.x;
    V.y = (fabsf(V.y) > 1.0f) ? 0.0f : V.y;
    V.z = (fabsf(V.z) > 1.0f) ? 0.0f : V.z;
    V.w = (fabsf(V.w) > 1.0f) ? 0.0f : V.w;
}

__global__ __launch_bounds__(THREADS) void SpikeLayer_88553635709313_kernel(
    const f32x4* __restrict__ in, f32x4* __restrict__ out) {
    const long long base =
        (long long)blockIdx.x * (THREADS * K) + threadIdx.x;  // k=0 column
    const f32x4* __restrict__ ip = in + base;
    f32x4* __restrict__ op = out + base;

    f32x4 V[K];
#pragma unroll
    for (int k = 0; k < K; ++k) V[k] = (f32x4)0.0f;

    for (int t = 0; t < TIMES; ++t) {
        const long long toff = (long long)t * STEP_F4;
        f32x4 I[K];
        // 8 back-to-back wave-loads: one contiguous 64-KB block-run per slice.
#pragma unroll
        for (int k = 0; k < K; ++k) I[k] = ip[toff + k * THREADS];
#pragma unroll
        for (int k = 0; k < K; ++k) {
            step_reset(V[k], I[k]);
            op[toff + k * THREADS] = V[k];
        }
    }
}

extern "C" void kernel_launch(void* const* d_in, const int* in_sizes, int n_in,
                              void* d_out, int out_size, void* d_ws, size_t ws_size,
                              hipStream_t stream) {
    const f32x4* in = (const f32x4*)d_in[0];
    f32x4* out = (f32x4*)d_out;
    const int blocks = (int)(STEP_F4 / (THREADS * K));  // 256
    SpikeLayer_88553635709313_kernel<<<blocks, THREADS, 0, stream>>>(in, out);
}